// Round 1
// baseline (456.684 us; speedup 1.0000x reference)
//
#include <hip/hip_runtime.h>
#include <hip/hip_bf16.h>
#include <stdint.h>

// Problem constants
#define BB 4
#define SS 2048
#define DD 1024
#define HH 16
#define HD 64
#define FF 4096
#define MM (BB * SS)   // 8192
#define BH (BB * HH)   // 64

typedef __bf16 bf16x8 __attribute__((ext_vector_type(8)));
typedef float f32x4 __attribute__((ext_vector_type(4)));

static __device__ __forceinline__ unsigned short f2bf(float f) {
  union { float f; unsigned u; } v; v.f = f;
  unsigned r = v.u + 0x7fffu + ((v.u >> 16) & 1u);
  return (unsigned short)(r >> 16);
}

// async global->LDS, 16B per lane. Dest must be wave-uniform base; HW adds lane*16.
#define GLD_LDS16(SRC, DST)                                          \
  __builtin_amdgcn_global_load_lds(                                  \
      (const __attribute__((address_space(1))) void*)(SRC),          \
      (__attribute__((address_space(3))) void*)(DST), 16, 0, 0)

// ---------------- cast f32 -> bf16 (x) ----------------
__global__ __launch_bounds__(256) void cast_bf16_k(const float* __restrict__ in,
                                                   unsigned short* __restrict__ out) {
  size_t i = ((size_t)blockIdx.x * 256 + threadIdx.x) * 4;
  float4 v = *(const float4*)(in + i);
  ushort4 u;
  u.x = f2bf(v.x); u.y = f2bf(v.y); u.z = f2bf(v.z); u.w = f2bf(v.w);
  *(ushort4*)(out + i) = u;
}

// ---------------- transpose + cast: W[K][N] f32 -> WT[N][K] bf16 ----------------
__global__ __launch_bounds__(256) void transpose_cast_k(const float* __restrict__ in,
                                                        unsigned short* __restrict__ out,
                                                        int K, int N) {
  __shared__ float tile[32][33];
  int n0 = blockIdx.x * 32, k0 = blockIdx.y * 32;
  int tx = threadIdx.x, ty = threadIdx.y;
#pragma unroll
  for (int i = 0; i < 32; i += 8)
    tile[ty + i][tx] = in[(size_t)(k0 + ty + i) * N + n0 + tx];
  __syncthreads();
#pragma unroll
  for (int i = 0; i < 32; i += 8)
    out[(size_t)(n0 + ty + i) * K + k0 + tx] = f2bf(tile[tx][ty + i]);
}

// ---------------- GEMM: C[M][N] = A[M][K] * BT[N][K]^T  (bf16 in, f32 accum) ----------
// 128x128 tile, BK=64, 4 waves (2x2), per-wave 4x4 fragments of 16x16x32 MFMA.
// LDS tiles XOR-swizzled on 16B chunks: slot(row,j) holds logical chunk j^(row&7).
// EPI: 0 = f32 plain; 1 = bf16 scatter (B,H,S,HD); 2 = bf16 scatter (B,H,HD,S);
//      3 = +bias, relu, bf16 plain; 4 = +bias, f32 plain.
template <int EPI>
__global__ __launch_bounds__(256, 2) void gemm_bt(const unsigned short* __restrict__ A,
                                                  const unsigned short* __restrict__ BT,
                                                  const float* __restrict__ bias,
                                                  void* __restrict__ Cout,
                                                  int N, int K) {
  __shared__ __align__(16) unsigned short Al[128 * 64];
  __shared__ __align__(16) unsigned short Bl[128 * 64];
  const int t = threadIdx.x;
  const int w = t >> 6, l = t & 63, lr = l & 15, lg = l >> 4;
  const int brow = blockIdx.y << 7, bcol = blockIdx.x << 7;
  const int wr = w >> 1, wc = w & 1;
  f32x4 acc[4][4] = {};

  for (int kt = 0; kt < K; kt += 64) {
    __syncthreads();  // previous tile's reads done before overwrite
#pragma unroll
    for (int is = 0; is < 4; ++is) {
      int c = is * 256 + t;          // chunk index 0..1023 (16B chunks)
      int row = c >> 3;
      int js = (c & 7) ^ (row & 7);  // inverse-swizzled source chunk
      GLD_LDS16(A + (size_t)(brow + row) * K + kt + js * 8,
                &Al[(size_t)(is * 256 + w * 64) * 8]);
      GLD_LDS16(BT + (size_t)(bcol + row) * K + kt + js * 8,
                &Bl[(size_t)(is * 256 + w * 64) * 8]);
    }
    __syncthreads();  // compiler drains vmcnt(0) before barrier
#pragma unroll
    for (int kk = 0; kk < 2; ++kk) {
      bf16x8 af[4], bfr[4];
#pragma unroll
      for (int m = 0; m < 4; ++m) {
        int row = wr * 64 + m * 16 + lr;
        af[m] = *(const bf16x8*)&Al[row * 64 + (((kk * 4 + lg) ^ (row & 7)) << 3)];
      }
#pragma unroll
      for (int n = 0; n < 4; ++n) {
        int row = wc * 64 + n * 16 + lr;
        bfr[n] = *(const bf16x8*)&Bl[row * 64 + (((kk * 4 + lg) ^ (row & 7)) << 3)];
      }
#pragma unroll
      for (int m = 0; m < 4; ++m)
#pragma unroll
        for (int n = 0; n < 4; ++n)
          acc[m][n] = __builtin_amdgcn_mfma_f32_16x16x32_bf16(af[m], bfr[n], acc[m][n], 0, 0, 0);
    }
  }

  // epilogue: C/D layout row=(l>>4)*4+i, col=l&15  (HW-verified)
#pragma unroll
  for (int m = 0; m < 4; ++m) {
#pragma unroll
    for (int n = 0; n < 4; ++n) {
      int col = bcol + wc * 64 + n * 16 + lr;
      float bv = 0.f;
      if (EPI == 3 || EPI == 4) bv = bias[col];
#pragma unroll
      for (int i = 0; i < 4; ++i) {
        int row = brow + wr * 64 + m * 16 + lg * 4 + i;
        float v = acc[m][n][i];
        if (EPI == 0) {
          ((float*)Cout)[(size_t)row * N + col] = v;
        } else if (EPI == 1) {  // (B,H,S,HD)
          int b = row >> 11, s = row & 2047, h = col >> 6, hd = col & 63;
          ((unsigned short*)Cout)[(((size_t)(b * HH + h)) * SS + s) * HD + hd] = f2bf(v);
        } else if (EPI == 2) {  // (B,H,HD,S)
          int b = row >> 11, s = row & 2047, h = col >> 6, hd = col & 63;
          ((unsigned short*)Cout)[(((size_t)(b * HH + h)) * HD + hd) * SS + s] = f2bf(v);
        } else if (EPI == 3) {
          v += bv; v = v > 0.f ? v : 0.f;
          ((unsigned short*)Cout)[(size_t)row * N + col] = f2bf(v);
        } else {
          v += bv;
          ((float*)Cout)[(size_t)row * N + col] = v;
        }
      }
    }
  }
}

// ---------------- flash attention ----------------
// grid (S/64, B*H); 4 waves, each owns 16 q rows. KVBLK=64, HD=64.
// Q (B,H,S,HD) bf16 hoisted to regs; K (B,H,S,HD); V pre-transposed (B,H,HD,S).
__global__ __launch_bounds__(256, 2) void attn_kernel(const unsigned short* __restrict__ Q,
                                                      const unsigned short* __restrict__ Kg,
                                                      const unsigned short* __restrict__ VT,
                                                      const int* __restrict__ vlens,
                                                      unsigned short* __restrict__ O) {
  __shared__ __align__(16) unsigned short Kt[64 * 64];
  __shared__ __align__(16) unsigned short Vt[64 * 64];
  __shared__ __align__(16) unsigned short Pt[4][16 * 64];
  const int t = threadIdx.x;
  const int w = t >> 6, l = t & 63, lr = l & 15, lg = l >> 4;
  const int bh = blockIdx.y, b = bh >> 4, h = bh & 15;
  const int q0 = blockIdx.x << 6;
  const int vl = vlens[b];
  const size_t base = (size_t)bh * SS * HD;

  bf16x8 qf[2];
  {
    const int qrow = q0 + w * 16 + lr;
    qf[0] = *(const bf16x8*)(Q + base + (size_t)qrow * HD + lg * 8);
    qf[1] = *(const bf16x8*)(Q + base + (size_t)qrow * HD + 32 + lg * 8);
  }
  f32x4 o[4] = {};
  float m_i[4], l_i[4];
#pragma unroll
  for (int i = 0; i < 4; ++i) { m_i[i] = -3.0e38f; l_i[i] = 0.f; }

  const int nkv = (vl + 63) >> 6;
  for (int kbi = 0; kbi < nkv; ++kbi) {
    const int kb = kbi << 6;
    __syncthreads();
#pragma unroll
    for (int is = 0; is < 2; ++is) {
      int c = is * 256 + t;          // 512 chunks per 8KB tile
      int row = c >> 3;
      int js = (c & 7) ^ (row & 7);
      GLD_LDS16(Kg + base + (size_t)(kb + row) * HD + js * 8,
                &Kt[(is * 256 + w * 64) * 8]);
      GLD_LDS16(VT + base + (size_t)row * SS + kb + js * 8,
                &Vt[(is * 256 + w * 64) * 8]);
    }
    __syncthreads();

    // QK^T: s[n] D-layout row(q)=lg*4+i, col(key)=n*16+lr
    f32x4 s[4] = {};
#pragma unroll
    for (int kk = 0; kk < 2; ++kk)
#pragma unroll
      for (int n = 0; n < 4; ++n) {
        int row = n * 16 + lr;
        bf16x8 kf = *(const bf16x8*)&Kt[row * 64 + (((kk * 4 + lg) ^ (row & 7)) << 3)];
        s[n] = __builtin_amdgcn_mfma_f32_16x16x32_bf16(qf[kk], kf, s[n], 0, 0, 0);
      }

    // online softmax (f32)
#pragma unroll
    for (int i = 0; i < 4; ++i) {
      float rm = -3.0e38f;
#pragma unroll
      for (int n = 0; n < 4; ++n) {
        float sv = s[n][i] * 0.125f;  // 1/sqrt(64)
        if (kb + n * 16 + lr >= vl) sv = -3.0e38f;
        s[n][i] = sv;
        rm = fmaxf(rm, sv);
      }
      rm = fmaxf(rm, __shfl_xor(rm, 1));
      rm = fmaxf(rm, __shfl_xor(rm, 2));
      rm = fmaxf(rm, __shfl_xor(rm, 4));
      rm = fmaxf(rm, __shfl_xor(rm, 8));
      float mnew = fmaxf(m_i[i], rm);
      float alpha = __expf(m_i[i] - mnew);
      float rs = 0.f;
#pragma unroll
      for (int n = 0; n < 4; ++n) {
        float p = __expf(s[n][i] - mnew);
        s[n][i] = p;
        rs += p;
      }
      rs += __shfl_xor(rs, 1);
      rs += __shfl_xor(rs, 2);
      rs += __shfl_xor(rs, 4);
      rs += __shfl_xor(rs, 8);
      l_i[i] = l_i[i] * alpha + rs;
      m_i[i] = mnew;
#pragma unroll
      for (int n = 0; n < 4; ++n) o[n][i] *= alpha;
    }

    // P (D-layout) -> per-wave LDS (swizzled), then reread as A-frag
#pragma unroll
    for (int n = 0; n < 4; ++n) {
      int colc = n * 2 + (lr >> 3);
      int cl = lr & 7;
#pragma unroll
      for (int i = 0; i < 4; ++i) {
        int row = lg * 4 + i;
        Pt[w][row * 64 + ((colc ^ (row & 7)) << 3) + cl] = f2bf(s[n][i]);
      }
    }
    // PV: o[n] += P * V   (B-operand = Vt rows, d = n*16+lr)
#pragma unroll
    for (int kk = 0; kk < 2; ++kk) {
      bf16x8 pf = *(const bf16x8*)&Pt[w][lr * 64 + (((kk * 4 + lg) ^ (lr & 7)) << 3)];
#pragma unroll
      for (int n = 0; n < 4; ++n) {
        int row = n * 16 + lr;
        bf16x8 vf = *(const bf16x8*)&Vt[row * 64 + (((kk * 4 + lg) ^ (row & 7)) << 3)];
        o[n] = __builtin_amdgcn_mfma_f32_16x16x32_bf16(pf, vf, o[n], 0, 0, 0);
      }
    }
  }

  float inv[4];
#pragma unroll
  for (int i = 0; i < 4; ++i) inv[i] = 1.f / l_i[i];
#pragma unroll
  for (int n = 0; n < 4; ++n)
#pragma unroll
    for (int i = 0; i < 4; ++i) {
      int qrow = q0 + w * 16 + lg * 4 + i;
      O[((size_t)b * SS + qrow) * DD + h * HD + n * 16 + lr] = f2bf(o[n][i] * inv[i]);
    }
}

// ---------------- fused add + layernorm ----------------
// out = LN(a+b)*g + beta ; writes f32 (optional) and bf16 (optional)
__global__ __launch_bounds__(256) void ln_kernel(const float* __restrict__ a,
                                                 const float* __restrict__ bsrc,
                                                 const float* __restrict__ g,
                                                 const float* __restrict__ be,
                                                 float* __restrict__ outf,
                                                 unsigned short* __restrict__ outb) {
  const int row = blockIdx.x;
  const int t = threadIdx.x;
  const float4 av = ((const float4*)(a + (size_t)row * DD))[t];
  const float4 bv = ((const float4*)(bsrc + (size_t)row * DD))[t];
  float4 s;
  s.x = av.x + bv.x; s.y = av.y + bv.y; s.z = av.z + bv.z; s.w = av.w + bv.w;
  float sum = s.x + s.y + s.z + s.w;
  float sq = s.x * s.x + s.y * s.y + s.z * s.z + s.w * s.w;
#pragma unroll
  for (int mm = 1; mm < 64; mm <<= 1) {
    sum += __shfl_xor(sum, mm);
    sq += __shfl_xor(sq, mm);
  }
  __shared__ float red[8];
  const int w = t >> 6, l = t & 63;
  if (l == 0) { red[w] = sum; red[4 + w] = sq; }
  __syncthreads();
  sum = red[0] + red[1] + red[2] + red[3];
  sq = red[4] + red[5] + red[6] + red[7];
  const float mu = sum * (1.f / (float)DD);
  const float var = sq * (1.f / (float)DD) - mu * mu;
  const float rs = rsqrtf(var + 1e-5f);
  const float4 gv = ((const float4*)g)[t];
  const float4 bev = ((const float4*)be)[t];
  float4 y;
  y.x = (s.x - mu) * rs * gv.x + bev.x;
  y.y = (s.y - mu) * rs * gv.y + bev.y;
  y.z = (s.z - mu) * rs * gv.z + bev.z;
  y.w = (s.w - mu) * rs * gv.w + bev.w;
  if (outf) ((float4*)(outf + (size_t)row * DD))[t] = y;
  if (outb) {
    ushort4 u;
    u.x = f2bf(y.x); u.y = f2bf(y.y); u.z = f2bf(y.z); u.w = f2bf(y.w);
    ((ushort4*)(outb + (size_t)row * DD))[t] = u;
  }
}

// ---------------- host ----------------
extern "C" void kernel_launch(void* const* d_in, const int* in_sizes, int n_in,
                              void* d_out, int out_size, void* d_ws, size_t ws_size,
                              hipStream_t stream) {
  (void)in_sizes; (void)n_in; (void)out_size; (void)ws_size;
  const float* x = (const float*)d_in[0];
  const int* vlen = (const int*)d_in[1];
  const float* Wq = (const float*)d_in[2];
  const float* Wk = (const float*)d_in[3];
  const float* Wv = (const float*)d_in[4];
  const float* Wo = (const float*)d_in[5];
  const float* W1 = (const float*)d_in[6];
  const float* b1 = (const float*)d_in[7];
  const float* W2 = (const float*)d_in[8];
  const float* b2 = (const float*)d_in[9];
  const float* g1 = (const float*)d_in[10];
  const float* be1 = (const float*)d_in[11];
  const float* g2 = (const float*)d_in[12];
  const float* be2 = (const float*)d_in[13];
  float* out = (float*)d_out;

  char* ws = (char*)d_ws;
  size_t off = 0;
  auto alloc = [&](size_t bytes) {
    char* p = ws + off;
    off += (bytes + 255) & ~(size_t)255;
    return p;
  };
  unsigned short* xb = (unsigned short*)alloc((size_t)MM * DD * 2);
  unsigned short* WqT = (unsigned short*)alloc((size_t)DD * DD * 2);
  unsigned short* WkT = (unsigned short*)alloc((size_t)DD * DD * 2);
  unsigned short* WvT = (unsigned short*)alloc((size_t)DD * DD * 2);
  unsigned short* WoT = (unsigned short*)alloc((size_t)DD * DD * 2);
  unsigned short* W1T = (unsigned short*)alloc((size_t)FF * DD * 2);
  unsigned short* W2T = (unsigned short*)alloc((size_t)DD * FF * 2);
  unsigned short* Qb = (unsigned short*)alloc((size_t)MM * DD * 2);   // (B,H,S,HD)
  unsigned short* Kbb = (unsigned short*)alloc((size_t)MM * DD * 2);  // (B,H,S,HD)
  unsigned short* VTb = (unsigned short*)alloc((size_t)MM * DD * 2);  // (B,H,HD,S)
  unsigned short* attnb = (unsigned short*)alloc((size_t)MM * DD * 2);
  float* proj = (float*)alloc((size_t)MM * DD * 4);
  float* res1f = (float*)alloc((size_t)MM * DD * 4);
  unsigned short* res1b = (unsigned short*)alloc((size_t)MM * DD * 2);
  unsigned short* ff1 = Qb;  // alias: Qb..attnb contiguous = 67.1MB, all dead post-attn/Wo
  float* ff2 = proj;         // alias: proj dead after LN1

  cast_bf16_k<<<MM * DD / 1024, 256, 0, stream>>>(x, xb);
  transpose_cast_k<<<dim3(32, 32), dim3(32, 8), 0, stream>>>(Wq, WqT, DD, DD);
  transpose_cast_k<<<dim3(32, 32), dim3(32, 8), 0, stream>>>(Wk, WkT, DD, DD);
  transpose_cast_k<<<dim3(32, 32), dim3(32, 8), 0, stream>>>(Wv, WvT, DD, DD);
  transpose_cast_k<<<dim3(32, 32), dim3(32, 8), 0, stream>>>(Wo, WoT, DD, DD);
  transpose_cast_k<<<dim3(128, 32), dim3(32, 8), 0, stream>>>(W1, W1T, DD, FF);
  transpose_cast_k<<<dim3(32, 128), dim3(32, 8), 0, stream>>>(W2, W2T, FF, DD);

  gemm_bt<1><<<dim3(8, 64), 256, 0, stream>>>(xb, WqT, nullptr, Qb, DD, DD);
  gemm_bt<1><<<dim3(8, 64), 256, 0, stream>>>(xb, WkT, nullptr, Kbb, DD, DD);
  gemm_bt<2><<<dim3(8, 64), 256, 0, stream>>>(xb, WvT, nullptr, VTb, DD, DD);

  attn_kernel<<<dim3(SS / 64, BH), 256, 0, stream>>>(Qb, Kbb, VTb, vlen, attnb);

  gemm_bt<0><<<dim3(8, 64), 256, 0, stream>>>(attnb, WoT, nullptr, proj, DD, DD);
  ln_kernel<<<MM, 256, 0, stream>>>(proj, x, g1, be1, res1f, res1b);
  gemm_bt<3><<<dim3(32, 64), 256, 0, stream>>>(res1b, W1T, b1, ff1, FF, DD);
  gemm_bt<4><<<dim3(8, 64), 256, 0, stream>>>(ff1, W2T, b2, ff2, DD, FF);
  ln_kernel<<<MM, 256, 0, stream>>>(ff2, res1f, g2, be2, out, nullptr);
}